// Round 1
// baseline (467.830 us; speedup 1.0000x reference)
//
#include <hip/hip_runtime.h>
#include <hip/hip_bf16.h>
#include <stdint.h>

typedef __attribute__((ext_vector_type(8))) short short8;
typedef __attribute__((ext_vector_type(4))) float f32x4;

#define NSLICE 8
#define SLICE_J 1024
#define CHUNKS 16   // SLICE_J / 64
#define L2E 1.44269504f

static __device__ __forceinline__ short f2bf(float f) {
    unsigned int u = __float_as_uint(f);
    u += 0x7fffu + ((u >> 16) & 1u);   // RNE
    return (short)(u >> 16);
}

// masked exp weight in fp32; accumulates fp32 denominator partial
static __device__ __forceinline__ float wfloat(int a, float e2s, float e1s, float& lsum) {
    float x = e1s + e2s;
    x = fmaf(0.4f, fabsf(x), 0.6f * x);          // leaky relu: 0.6x + 0.4|x| (2 VALU, abs is free mod)
    float w = __builtin_amdgcn_exp2f(x);          // v_exp_f32 (2^x)
    w = (a > 0) ? w : 0.f;
    lsum += w;
    return w;
}

// pack two fp32 -> one u32 of 2x bf16, RNE (identical rounding to f2bf)
static __device__ __forceinline__ unsigned pkbf16(float lo, float hi) {
    unsigned r;
    asm("v_cvt_pk_bf16_f32 %0, %1, %2" : "=v"(r) : "v"(lo), "v"(hi));
    return r;
}

// ---------------- Phase 1a: Wh partials, K split 4 ways for occupancy ----------
// grid 2048 = 512 row-groups x 4 k-slices; 32 waves/CU (was 8) -> latency hidden.
__global__ __launch_bounds__(256)
void gat_wh_part(const float* __restrict__ h, const float* __restrict__ W,
                 float* __restrict__ whp)
{
    const int lane = threadIdx.x & 63;
    const int wave = threadIdx.x >> 6;
    const int ks   = blockIdx.x & 3;
    const int row0 = (blockIdx.x >> 2) * 16 + wave * 4;
    const int c0   = ks * 128;

    float acc[4] = {0.f, 0.f, 0.f, 0.f};
#pragma unroll 8
    for (int ci = 0; ci < 128; ++ci) {
        const int c = c0 + ci;
        const float wv = W[c * 64 + lane];          // coalesced, L2-hot
#pragma unroll
        for (int r = 0; r < 4; ++r)                 // h index wave-uniform -> s_load
            acc[r] += h[(size_t)(row0 + r) * 512 + c] * wv;
    }
#pragma unroll
    for (int r = 0; r < 4; ++r)
        whp[((size_t)ks << 19) + (size_t)(row0 + r) * 64 + lane] = acc[r];
}

// ---------------- Phase 1b: merge partials -> e1,e2 (fp32) + packed whT --------
// whT layout (shorts): tile(=j>>6)*4096 + ((n>>4)*2 + frag)*512 + qk*128 + (n&15)*8 + t
//   where j = node, n = feature, kin = j&63, frag = kin>>5, qk = (kin>>3)&3, t = kin&7.
__global__ __launch_bounds__(256)
void gat_pack(const float* __restrict__ whp, const float* __restrict__ a,
              short* __restrict__ whT, float* __restrict__ e1, float* __restrict__ e2)
{
    const int lane = threadIdx.x & 63;
    const int wave = threadIdx.x >> 6;
    const int row  = blockIdx.x * 4 + wave;

    float acc = 0.f;
#pragma unroll
    for (int ks = 0; ks < 4; ++ks)
        acc += whp[((size_t)ks << 19) + (size_t)row * 64 + lane];

    float p1 = acc * a[lane];
    float p2 = acc * a[64 + lane];
#pragma unroll
    for (int off = 32; off; off >>= 1) {
        p1 += __shfl_xor(p1, off);
        p2 += __shfl_xor(p2, off);
    }
    if (lane == 0) { e1[row] = p1; e2[row] = p2; }

    const int kin = row & 63;
    const int frag = (kin >> 5) & 1, qk = (kin >> 3) & 3, t = kin & 7;
    whT[(size_t)(row >> 6) * 4096 + ((lane >> 4) * 2 + frag) * 512 + qk * 128
        + (lane & 15) * 8 + t] = f2bf(acc);
}

// ---------------- Phase 2: fused masked exp + P@Wh (no-max softmax, split-j) --
// adj prefetched one chunk ahead in registers; bf16 pack via v_cvt_pk_bf16_f32.
__global__ __launch_bounds__(256, 4)
void gat_attn(const int* __restrict__ adj, const short* __restrict__ whT,
              const float* __restrict__ e1, const float* __restrict__ e2,
              float* __restrict__ lpart, float* __restrict__ opart)
{
    __shared__ float se2[SLICE_J];
    const int bid = blockIdx.x;
    const int s   = bid & (NSLICE - 1);
    const int rb  = bid >> 3;
    const int tid = threadIdx.x;

    {
        float4 v = *reinterpret_cast<const float4*>(e2 + s * SLICE_J + tid * 4);
        v.x *= L2E; v.y *= L2E; v.z *= L2E; v.w *= L2E;
        *reinterpret_cast<float4*>(se2 + tid * 4) = v;
    }
    __syncthreads();

    const int lane = tid & 63;
    const int wave = tid >> 6;
    const int quad = lane >> 4;
    const int r16  = lane & 15;
    const int rowBase = rb * 64 + wave * 16;
    const int row  = rowBase + r16;
    const float e1s = e1[row] * L2E;
    const int* __restrict__ arow = adj + (size_t)row * 8192 + s * SLICE_J + quad * 8;

    float lsa = 0.f, lsb = 0.f;
    f32x4 acc[4];
#pragma unroll
    for (int ff = 0; ff < 4; ++ff) acc[ff] = (f32x4){0.f, 0.f, 0.f, 0.f};

    // prologue: chunk 0 adj in registers
    int4 A0 = *reinterpret_cast<const int4*>(arow + 0);
    int4 A1 = *reinterpret_cast<const int4*>(arow + 4);
    int4 A2 = *reinterpret_cast<const int4*>(arow + 32);
    int4 A3 = *reinterpret_cast<const int4*>(arow + 36);

    for (int ch = 0; ch < CHUNKS; ++ch) {
        // prefetch next chunk (wraps to chunk 0 on last iter: L2-hit, harmless)
        const int jn = ((ch + 1) & (CHUNKS - 1)) * 64;
        const int4 N0 = *reinterpret_cast<const int4*>(arow + jn + 0);
        const int4 N1 = *reinterpret_cast<const int4*>(arow + jn + 4);
        const int4 N2 = *reinterpret_cast<const int4*>(arow + jn + 32);
        const int4 N3 = *reinterpret_cast<const int4*>(arow + jn + 36);

        const int j0 = ch * 64 + quad * 8;
        const float4 E0 = *reinterpret_cast<const float4*>(se2 + j0);
        const float4 E1 = *reinterpret_cast<const float4*>(se2 + j0 + 4);
        const float4 E2 = *reinterpret_cast<const float4*>(se2 + j0 + 32);
        const float4 E3 = *reinterpret_cast<const float4*>(se2 + j0 + 36);

        union U { unsigned u[4]; short8 s8; };
        U af0, af1;
        {
            const float w0 = wfloat(A0.x, E0.x, e1s, lsa);
            const float w1 = wfloat(A0.y, E0.y, e1s, lsa);
            const float w2 = wfloat(A0.z, E0.z, e1s, lsa);
            const float w3 = wfloat(A0.w, E0.w, e1s, lsa);
            const float w4 = wfloat(A1.x, E1.x, e1s, lsa);
            const float w5 = wfloat(A1.y, E1.y, e1s, lsa);
            const float w6 = wfloat(A1.z, E1.z, e1s, lsa);
            const float w7 = wfloat(A1.w, E1.w, e1s, lsa);
            af0.u[0] = pkbf16(w0, w1);
            af0.u[1] = pkbf16(w2, w3);
            af0.u[2] = pkbf16(w4, w5);
            af0.u[3] = pkbf16(w6, w7);
        }
        {
            const float w0 = wfloat(A2.x, E2.x, e1s, lsb);
            const float w1 = wfloat(A2.y, E2.y, e1s, lsb);
            const float w2 = wfloat(A2.z, E2.z, e1s, lsb);
            const float w3 = wfloat(A2.w, E2.w, e1s, lsb);
            const float w4 = wfloat(A3.x, E3.x, e1s, lsb);
            const float w5 = wfloat(A3.y, E3.y, e1s, lsb);
            const float w6 = wfloat(A3.z, E3.z, e1s, lsb);
            const float w7 = wfloat(A3.w, E3.w, e1s, lsb);
            af1.u[0] = pkbf16(w0, w1);
            af1.u[1] = pkbf16(w2, w3);
            af1.u[2] = pkbf16(w4, w5);
            af1.u[3] = pkbf16(w6, w7);
        }

        // B-fragment loads: whT pre-permuted -> 64 lanes x 16 B contiguous per load
        const short* wtile = whT + (size_t)(s * 16 + ch) * 4096 + lane * 8;
#pragma unroll
        for (int ff = 0; ff < 4; ++ff) {
            const short8 b0 = *reinterpret_cast<const short8*>(wtile + (ff * 2 + 0) * 512);
            const short8 b1 = *reinterpret_cast<const short8*>(wtile + (ff * 2 + 1) * 512);
            acc[ff] = __builtin_amdgcn_mfma_f32_16x16x32_bf16(af0.s8, b0, acc[ff], 0, 0, 0);
            acc[ff] = __builtin_amdgcn_mfma_f32_16x16x32_bf16(af1.s8, b1, acc[ff], 0, 0, 0);
        }

        A0 = N0; A1 = N1; A2 = N2; A3 = N3;
    }

    // denominator partial: reduce across the 4 quads holding the same row
    float lsum = lsa + lsb;
    lsum += __shfl_xor(lsum, 16);
    lsum += __shfl_xor(lsum, 32);
    if (lane < 16) lpart[s * 8192 + rowBase + lane] = lsum;

#pragma unroll
    for (int ff = 0; ff < 4; ++ff) {
#pragma unroll
        for (int rg = 0; rg < 4; ++rg) {
            const int orow = rowBase + quad * 4 + rg;
            const int ocol = ff * 16 + r16;
            opart[((size_t)s * 8192 + orow) * 64 + ocol] = acc[ff][rg];
        }
    }
}

// ---------------- Phase 3: merge slice partials, normalize, ELU ----------------
__global__ __launch_bounds__(256)
void gat_combine(const float* __restrict__ lpart, const float* __restrict__ opart,
                 float* __restrict__ out)
{
    const int gid = blockIdx.x * 256 + threadIdx.x;
    const int row = gid >> 6;
    const int f   = gid & 63;

    float lsum = 0.f, osum = 0.f;
#pragma unroll
    for (int s = 0; s < NSLICE; ++s) {
        lsum += lpart[s * 8192 + row];
        osum += opart[((size_t)s * 8192 + row) * 64 + f];
    }
    const float v = osum / lsum;
    out[gid] = (v > 0.f) ? v : (__expf(v) - 1.f);
}

extern "C" void kernel_launch(void* const* d_in, const int* in_sizes, int n_in,
                              void* d_out, int out_size, void* d_ws, size_t ws_size,
                              hipStream_t stream) {
    const float* h   = (const float*)d_in[0];
    const int*   adj = (const int*)d_in[1];
    const float* W   = (const float*)d_in[2];
    const float* a   = (const float*)d_in[3];
    float* out = (float*)d_out;

    char* ws = (char*)d_ws;
    short* whT   = (short*)ws;                                   // 1 MB
    float* e1    = (float*)(ws + (1u << 20));                    // 32 KB
    float* e2    = (float*)(ws + (1u << 20) + (32u << 10));      // 32 KB
    float* lpart = (float*)(ws + (1u << 20) + (64u << 10));      // 256 KB
    float* opart = (float*)(ws + (2u << 20));                    // 16 MB
    float* whp   = (float*)(ws + (32u << 20));                   // 8 MB fp32 Wh partials

    gat_wh_part<<<2048, 256, 0, stream>>>(h, W, whp);
    gat_pack<<<2048, 256, 0, stream>>>(whp, a, whT, e1, e2);
    gat_attn<<<128 * NSLICE, 256, 0, stream>>>(adj, whT, e1, e2, lpart, opart);
    gat_combine<<<out_size / 256, 256, 0, stream>>>(lpart, opart, out);
}

// Round 2
// 459.640 us; speedup vs baseline: 1.0178x; 1.0178x over previous
//
#include <hip/hip_runtime.h>
#include <hip/hip_bf16.h>
#include <stdint.h>

typedef __attribute__((ext_vector_type(8))) short short8;
typedef __attribute__((ext_vector_type(4))) float f32x4;

#define NSLICE 8
#define SLICE_J 1024
#define CHUNKS 16   // SLICE_J / 64
#define L2E 1.44269504f

static __device__ __forceinline__ short f2bf(float f) {
    unsigned int u = __float_as_uint(f);
    u += 0x7fffu + ((u >> 16) & 1u);   // RNE
    return (short)(u >> 16);
}

// masked exp weight in fp32; accumulates fp32 denominator partial
static __device__ __forceinline__ float wfloat(int a, float e2s, float e1s, float& lsum) {
    float x = e1s + e2s;
    x = fmaf(0.4f, fabsf(x), 0.6f * x);          // leaky relu: 0.6x + 0.4|x|
    float w = __builtin_amdgcn_exp2f(x);          // v_exp_f32 (2^x)
    w = (a > 0) ? w : 0.f;
    lsum += w;
    return w;
}

// pack two fp32 -> one u32 of 2x bf16, RNE (identical rounding to f2bf)
static __device__ __forceinline__ unsigned pkbf16(float lo, float hi) {
    unsigned r;
    asm("v_cvt_pk_bf16_f32 %0, %1, %2" : "=v"(r) : "v"(lo), "v"(hi));
    return r;
}

// ---------------- Phase 1: Wh = h@W -> e1, e2 (fp32), whT in B-fragment tiles --
// 2048 blocks x 4 waves, ONE row per wave: 8 blocks/CU = 32 waves/CU (occupancy
// without any intermediate round-trip). W stream is L2-hot; h is a wave-uniform
// scalar stream read exactly once.
// whT layout (shorts): tile(=j>>6)*4096 + ((n>>4)*2 + frag)*512 + qk*128 + (n&15)*8 + t
//   where j = node, n = feature, kin = j&63, frag = kin>>5, qk = (kin>>3)&3, t = kin&7.
__global__ __launch_bounds__(256)
void gat_wh(const float* __restrict__ h, const float* __restrict__ W,
            const float* __restrict__ a, short* __restrict__ whT,
            float* __restrict__ e1, float* __restrict__ e2)
{
    const int lane = threadIdx.x & 63;
    const int wave = threadIdx.x >> 6;
    const int row  = blockIdx.x * 4 + wave;

    float acc = 0.f;
#pragma unroll 8
    for (int c = 0; c < 512; ++c)
        acc += h[(size_t)row * 512 + c] * W[c * 64 + lane];

    float p1 = acc * a[lane];
    float p2 = acc * a[64 + lane];
#pragma unroll
    for (int off = 32; off; off >>= 1) {
        p1 += __shfl_xor(p1, off);
        p2 += __shfl_xor(p2, off);
    }
    if (lane == 0) { e1[row] = p1; e2[row] = p2; }

    const int kin = row & 63;
    const int frag = (kin >> 5) & 1, qk = (kin >> 3) & 3, t = kin & 7;
    whT[(size_t)(row >> 6) * 4096 + ((lane >> 4) * 2 + frag) * 512 + qk * 128
        + (lane & 15) * 8 + t] = f2bf(acc);
}

// ---------------- Phase 2: fused masked exp + P@Wh (no-max softmax, split-j) --
// adj prefetched one chunk ahead in registers; bf16 pack via v_cvt_pk_bf16_f32.
// NO second launch_bounds arg: round 1 showed pinning 4 blocks/CU with the
// prefetch registers live causes spills (+34 us).
__global__ __launch_bounds__(256)
void gat_attn(const int* __restrict__ adj, const short* __restrict__ whT,
              const float* __restrict__ e1, const float* __restrict__ e2,
              float* __restrict__ lpart, float* __restrict__ opart)
{
    __shared__ float se2[SLICE_J];
    const int bid = blockIdx.x;
    const int s   = bid & (NSLICE - 1);
    const int rb  = bid >> 3;
    const int tid = threadIdx.x;

    {
        float4 v = *reinterpret_cast<const float4*>(e2 + s * SLICE_J + tid * 4);
        v.x *= L2E; v.y *= L2E; v.z *= L2E; v.w *= L2E;
        *reinterpret_cast<float4*>(se2 + tid * 4) = v;
    }
    __syncthreads();

    const int lane = tid & 63;
    const int wave = tid >> 6;
    const int quad = lane >> 4;
    const int r16  = lane & 15;
    const int rowBase = rb * 64 + wave * 16;
    const int row  = rowBase + r16;
    const float e1s = e1[row] * L2E;
    const int* __restrict__ arow = adj + (size_t)row * 8192 + s * SLICE_J + quad * 8;

    float lsa = 0.f, lsb = 0.f;
    f32x4 acc[4];
#pragma unroll
    for (int ff = 0; ff < 4; ++ff) acc[ff] = (f32x4){0.f, 0.f, 0.f, 0.f};

    // prologue: chunk 0 adj in registers
    int4 A0 = *reinterpret_cast<const int4*>(arow + 0);
    int4 A1 = *reinterpret_cast<const int4*>(arow + 4);
    int4 A2 = *reinterpret_cast<const int4*>(arow + 32);
    int4 A3 = *reinterpret_cast<const int4*>(arow + 36);

    for (int ch = 0; ch < CHUNKS; ++ch) {
        // prefetch next chunk (wraps to chunk 0 on last iter: L2-hit, harmless)
        const int jn = ((ch + 1) & (CHUNKS - 1)) * 64;
        const int4 N0 = *reinterpret_cast<const int4*>(arow + jn + 0);
        const int4 N1 = *reinterpret_cast<const int4*>(arow + jn + 4);
        const int4 N2 = *reinterpret_cast<const int4*>(arow + jn + 32);
        const int4 N3 = *reinterpret_cast<const int4*>(arow + jn + 36);

        const int j0 = ch * 64 + quad * 8;
        const float4 E0 = *reinterpret_cast<const float4*>(se2 + j0);
        const float4 E1 = *reinterpret_cast<const float4*>(se2 + j0 + 4);
        const float4 E2 = *reinterpret_cast<const float4*>(se2 + j0 + 32);
        const float4 E3 = *reinterpret_cast<const float4*>(se2 + j0 + 36);

        union U { unsigned u[4]; short8 s8; };
        U af0, af1;
        {
            const float w0 = wfloat(A0.x, E0.x, e1s, lsa);
            const float w1 = wfloat(A0.y, E0.y, e1s, lsa);
            const float w2 = wfloat(A0.z, E0.z, e1s, lsa);
            const float w3 = wfloat(A0.w, E0.w, e1s, lsa);
            const float w4 = wfloat(A1.x, E1.x, e1s, lsa);
            const float w5 = wfloat(A1.y, E1.y, e1s, lsa);
            const float w6 = wfloat(A1.z, E1.z, e1s, lsa);
            const float w7 = wfloat(A1.w, E1.w, e1s, lsa);
            af0.u[0] = pkbf16(w0, w1);
            af0.u[1] = pkbf16(w2, w3);
            af0.u[2] = pkbf16(w4, w5);
            af0.u[3] = pkbf16(w6, w7);
        }
        {
            const float w0 = wfloat(A2.x, E2.x, e1s, lsb);
            const float w1 = wfloat(A2.y, E2.y, e1s, lsb);
            const float w2 = wfloat(A2.z, E2.z, e1s, lsb);
            const float w3 = wfloat(A2.w, E2.w, e1s, lsb);
            const float w4 = wfloat(A3.x, E3.x, e1s, lsb);
            const float w5 = wfloat(A3.y, E3.y, e1s, lsb);
            const float w6 = wfloat(A3.z, E3.z, e1s, lsb);
            const float w7 = wfloat(A3.w, E3.w, e1s, lsb);
            af1.u[0] = pkbf16(w0, w1);
            af1.u[1] = pkbf16(w2, w3);
            af1.u[2] = pkbf16(w4, w5);
            af1.u[3] = pkbf16(w6, w7);
        }

        // B-fragment loads: whT pre-permuted -> 64 lanes x 16 B contiguous per load
        const short* wtile = whT + (size_t)(s * 16 + ch) * 4096 + lane * 8;
#pragma unroll
        for (int ff = 0; ff < 4; ++ff) {
            const short8 b0 = *reinterpret_cast<const short8*>(wtile + (ff * 2 + 0) * 512);
            const short8 b1 = *reinterpret_cast<const short8*>(wtile + (ff * 2 + 1) * 512);
            acc[ff] = __builtin_amdgcn_mfma_f32_16x16x32_bf16(af0.s8, b0, acc[ff], 0, 0, 0);
            acc[ff] = __builtin_amdgcn_mfma_f32_16x16x32_bf16(af1.s8, b1, acc[ff], 0, 0, 0);
        }

        A0 = N0; A1 = N1; A2 = N2; A3 = N3;
    }

    // denominator partial: reduce across the 4 quads holding the same row
    float lsum = lsa + lsb;
    lsum += __shfl_xor(lsum, 16);
    lsum += __shfl_xor(lsum, 32);
    if (lane < 16) lpart[s * 8192 + rowBase + lane] = lsum;

#pragma unroll
    for (int ff = 0; ff < 4; ++ff) {
#pragma unroll
        for (int rg = 0; rg < 4; ++rg) {
            const int orow = rowBase + quad * 4 + rg;
            const int ocol = ff * 16 + r16;
            opart[((size_t)s * 8192 + orow) * 64 + ocol] = acc[ff][rg];
        }
    }
}

// ---------------- Phase 3: merge slice partials, normalize, ELU ----------------
__global__ __launch_bounds__(256)
void gat_combine(const float* __restrict__ lpart, const float* __restrict__ opart,
                 float* __restrict__ out)
{
    const int gid = blockIdx.x * 256 + threadIdx.x;
    const int row = gid >> 6;
    const int f   = gid & 63;

    float lsum = 0.f, osum = 0.f;
#pragma unroll
    for (int s = 0; s < NSLICE; ++s) {
        lsum += lpart[s * 8192 + row];
        osum += opart[((size_t)s * 8192 + row) * 64 + f];
    }
    const float v = osum / lsum;
    out[gid] = (v > 0.f) ? v : (__expf(v) - 1.f);
}

extern "C" void kernel_launch(void* const* d_in, const int* in_sizes, int n_in,
                              void* d_out, int out_size, void* d_ws, size_t ws_size,
                              hipStream_t stream) {
    const float* h   = (const float*)d_in[0];
    const int*   adj = (const int*)d_in[1];
    const float* W   = (const float*)d_in[2];
    const float* a   = (const float*)d_in[3];
    float* out = (float*)d_out;

    char* ws = (char*)d_ws;
    short* whT   = (short*)ws;                                   // 1 MB
    float* e1    = (float*)(ws + (1u << 20));                    // 32 KB
    float* e2    = (float*)(ws + (1u << 20) + (32u << 10));      // 32 KB
    float* lpart = (float*)(ws + (1u << 20) + (64u << 10));      // 256 KB
    float* opart = (float*)(ws + (2u << 20));                    // 16 MB

    gat_wh<<<2048, 256, 0, stream>>>(h, W, a, whT, e1, e2);
    gat_attn<<<128 * NSLICE, 256, 0, stream>>>(adj, whT, e1, e2, lpart, opart);
    gat_combine<<<out_size / 256, 256, 0, stream>>>(lpart, opart, out);
}

// Round 3
// 434.935 us; speedup vs baseline: 1.0756x; 1.0568x over previous
//
#include <hip/hip_runtime.h>
#include <hip/hip_bf16.h>
#include <stdint.h>

typedef __attribute__((ext_vector_type(8))) short short8;
typedef __attribute__((ext_vector_type(4))) float f32x4;

#define NSLICE 8
#define SLICE_J 1024
#define CHUNKS 16   // SLICE_J / 64
#define L2E 1.44269504f

static __device__ __forceinline__ short f2bf(float f) {
    unsigned int u = __float_as_uint(f);
    u += 0x7fffu + ((u >> 16) & 1u);   // RNE
    return (short)(u >> 16);
}

// w = exp2(lrelu(e1s + e2s)) if a>0 else 0; accumulate lsum; return bf16(w).
// NOTE: keep scalar f2bf here — inline-asm v_cvt_pk_bf16_f32 measured SLOWER
// (compiler scheduling beats hand-pinned asm; rounds 1-2 regression).
static __device__ __forceinline__ short welem(int a, float e2s, float e1s, float& lsum) {
    float x = e1s + e2s;
    x = fmaxf(x, 0.f) + 0.2f * fminf(x, 0.f);    // leaky relu (scale-invariant)
    float w = __builtin_amdgcn_exp2f(x);          // v_exp_f32 (2^x)
    w = (a > 0) ? w : 0.f;
    lsum += w;
    return f2bf(w);
}

// ---------------- Phase 1: Wh = h@W -> e1, e2 (fp32), whT in B-fragment tiles --
// W staged in LDS (32 KB tile), read once per BLOCK from L2 instead of once per
// wave: removes the L2-latency-bound W stream that made r0's version slow.
// 512 blocks x 4 waves x 4 rows; one ds_read (256 B contiguous, conflict-free)
// feeds 4 rows' FMAs. Accumulation order over c unchanged -> bitwise-same Wh.
// whT layout (shorts): tile(=j>>6)*4096 + ((n>>4)*2 + frag)*512 + qk*128 + (n&15)*8 + t
//   where j = node, n = feature, kin = j&63, frag = kin>>5, qk = (kin>>3)&3, t = kin&7.
__global__ __launch_bounds__(256)
void gat_wh(const float* __restrict__ h, const float* __restrict__ W,
            const float* __restrict__ a, short* __restrict__ whT,
            float* __restrict__ e1, float* __restrict__ e2)
{
    __shared__ float sW[128][64];
    const int tid  = threadIdx.x;
    const int lane = tid & 63;
    const int wave = tid >> 6;
    const int row0 = blockIdx.x * 16 + wave * 4;

    float acc[4] = {0.f, 0.f, 0.f, 0.f};
#pragma unroll
    for (int t = 0; t < 4; ++t) {
        const int c0 = t * 128;
        // stage W[c0..c0+128) x 64 into LDS: 2048 float4, coalesced
        {
            const float4* src = reinterpret_cast<const float4*>(W + c0 * 64);
            float4* dst = reinterpret_cast<float4*>(&sW[0][0]);
#pragma unroll
            for (int k = 0; k < 8; ++k) dst[tid + k * 256] = src[tid + k * 256];
        }
        __syncthreads();
#pragma unroll 4
        for (int ci = 0; ci < 128; ++ci) {
            const float wv = sW[ci][lane];
#pragma unroll
            for (int r = 0; r < 4; ++r)                 // h index wave-uniform -> s_load
                acc[r] += h[(size_t)(row0 + r) * 512 + c0 + ci] * wv;
        }
        __syncthreads();
    }

    const float a1v = a[lane];
    const float a2v = a[64 + lane];
    const int f    = lane >> 4;
    const int r16n = lane & 15;
#pragma unroll
    for (int r = 0; r < 4; ++r) {
        float p1 = acc[r] * a1v;
        float p2 = acc[r] * a2v;
#pragma unroll
        for (int off = 32; off; off >>= 1) {
            p1 += __shfl_xor(p1, off);
            p2 += __shfl_xor(p2, off);
        }
        if (lane == 0) { e1[row0 + r] = p1; e2[row0 + r] = p2; }
        const int j = row0 + r;
        const int kin = j & 63;
        const int frag = (kin >> 5) & 1, qk = (kin >> 3) & 3, t = kin & 7;
        whT[(size_t)(j >> 6) * 4096 + (f * 2 + frag) * 512 + qk * 128 + r16n * 8 + t]
            = f2bf(acc[r]);
    }
}

// ---------------- Phase 2: fused masked exp + P@Wh (no-max softmax, split-j) --
// Round-0 form: no register prefetch, no inline-asm pack — both measured as
// regressions (rounds 1-2). Compiler's own scheduling wins here.
__global__ __launch_bounds__(256)
void gat_attn(const int* __restrict__ adj, const short* __restrict__ whT,
              const float* __restrict__ e1, const float* __restrict__ e2,
              float* __restrict__ lpart, float* __restrict__ opart)
{
    __shared__ float se2[SLICE_J];
    const int bid = blockIdx.x;
    const int s   = bid & (NSLICE - 1);
    const int rb  = bid >> 3;
    const int tid = threadIdx.x;

    // stage e2 slice into LDS, pre-scaled by log2(e)
    {
        float4 v = *reinterpret_cast<const float4*>(e2 + s * SLICE_J + tid * 4);
        v.x *= L2E; v.y *= L2E; v.z *= L2E; v.w *= L2E;
        *reinterpret_cast<float4*>(se2 + tid * 4) = v;
    }
    __syncthreads();

    const int lane = tid & 63;
    const int wave = tid >> 6;
    const int quad = lane >> 4;
    const int r16  = lane & 15;
    const int rowBase = rb * 64 + wave * 16;
    const int row  = rowBase + r16;
    const float e1s = e1[row] * L2E;
    const size_t adjRow = (size_t)row * 8192 + (size_t)s * SLICE_J;

    float lsum = 0.f;
    f32x4 acc[4];
#pragma unroll
    for (int ff = 0; ff < 4; ++ff) acc[ff] = (f32x4){0.f, 0.f, 0.f, 0.f};

    for (int ch = 0; ch < CHUNKS; ++ch) {
        const int j0 = ch * 64 + quad * 8;   // within-slice k-group for A-frag
        // adj directly in MFMA A-fragment layout: m=r16, k=quad*8+t (+32 for frag1)
        const int4 A0 = *reinterpret_cast<const int4*>(adj + adjRow + j0);
        const int4 A1 = *reinterpret_cast<const int4*>(adj + adjRow + j0 + 4);
        const int4 A2 = *reinterpret_cast<const int4*>(adj + adjRow + j0 + 32);
        const int4 A3 = *reinterpret_cast<const int4*>(adj + adjRow + j0 + 36);
        const float4 E0 = *reinterpret_cast<const float4*>(se2 + j0);
        const float4 E1 = *reinterpret_cast<const float4*>(se2 + j0 + 4);
        const float4 E2 = *reinterpret_cast<const float4*>(se2 + j0 + 32);
        const float4 E3 = *reinterpret_cast<const float4*>(se2 + j0 + 36);

        short8 af0, af1;
        af0[0] = welem(A0.x, E0.x, e1s, lsum);
        af0[1] = welem(A0.y, E0.y, e1s, lsum);
        af0[2] = welem(A0.z, E0.z, e1s, lsum);
        af0[3] = welem(A0.w, E0.w, e1s, lsum);
        af0[4] = welem(A1.x, E1.x, e1s, lsum);
        af0[5] = welem(A1.y, E1.y, e1s, lsum);
        af0[6] = welem(A1.z, E1.z, e1s, lsum);
        af0[7] = welem(A1.w, E1.w, e1s, lsum);
        af1[0] = welem(A2.x, E2.x, e1s, lsum);
        af1[1] = welem(A2.y, E2.y, e1s, lsum);
        af1[2] = welem(A2.z, E2.z, e1s, lsum);
        af1[3] = welem(A2.w, E2.w, e1s, lsum);
        af1[4] = welem(A3.x, E3.x, e1s, lsum);
        af1[5] = welem(A3.y, E3.y, e1s, lsum);
        af1[6] = welem(A3.z, E3.z, e1s, lsum);
        af1[7] = welem(A3.w, E3.w, e1s, lsum);

        // B-fragment loads: whT pre-permuted -> 64 lanes x 16 B contiguous per load
        const short* wtile = whT + (size_t)(s * 16 + ch) * 4096 + lane * 8;
#pragma unroll
        for (int ff = 0; ff < 4; ++ff) {
            const short8 b0 = *reinterpret_cast<const short8*>(wtile + (ff * 2 + 0) * 512);
            const short8 b1 = *reinterpret_cast<const short8*>(wtile + (ff * 2 + 1) * 512);
            acc[ff] = __builtin_amdgcn_mfma_f32_16x16x32_bf16(af0, b0, acc[ff], 0, 0, 0);
            acc[ff] = __builtin_amdgcn_mfma_f32_16x16x32_bf16(af1, b1, acc[ff], 0, 0, 0);
        }
    }

    // denominator partial: reduce across the 4 quads holding the same row
    lsum += __shfl_xor(lsum, 16);
    lsum += __shfl_xor(lsum, 32);
    if (lane < 16) lpart[s * 8192 + rowBase + lane] = lsum;

#pragma unroll
    for (int ff = 0; ff < 4; ++ff) {
#pragma unroll
        for (int rg = 0; rg < 4; ++rg) {
            const int orow = rowBase + quad * 4 + rg;
            const int ocol = ff * 16 + r16;
            opart[((size_t)s * 8192 + orow) * 64 + ocol] = acc[ff][rg];
        }
    }
}

// ---------------- Phase 3: merge slice partials, normalize, ELU ----------------
__global__ __launch_bounds__(256)
void gat_combine(const float* __restrict__ lpart, const float* __restrict__ opart,
                 float* __restrict__ out)
{
    const int gid = blockIdx.x * 256 + threadIdx.x;
    const int row = gid >> 6;
    const int f   = gid & 63;

    float lsum = 0.f, osum = 0.f;
#pragma unroll
    for (int s = 0; s < NSLICE; ++s) {
        lsum += lpart[s * 8192 + row];
        osum += opart[((size_t)s * 8192 + row) * 64 + f];
    }
    const float v = osum / lsum;
    out[gid] = (v > 0.f) ? v : (__expf(v) - 1.f);
}

extern "C" void kernel_launch(void* const* d_in, const int* in_sizes, int n_in,
                              void* d_out, int out_size, void* d_ws, size_t ws_size,
                              hipStream_t stream) {
    const float* h   = (const float*)d_in[0];
    const int*   adj = (const int*)d_in[1];
    const float* W   = (const float*)d_in[2];
    const float* a   = (const float*)d_in[3];
    float* out = (float*)d_out;

    char* ws = (char*)d_ws;
    short* whT   = (short*)ws;                                   // 1 MB
    float* e1    = (float*)(ws + (1u << 20));                    // 32 KB
    float* e2    = (float*)(ws + (1u << 20) + (32u << 10));      // 32 KB
    float* lpart = (float*)(ws + (1u << 20) + (64u << 10));      // 256 KB
    float* opart = (float*)(ws + (2u << 20));                    // 16 MB

    gat_wh<<<512, 256, 0, stream>>>(h, W, a, whT, e1, e2);
    gat_attn<<<128 * NSLICE, 256, 0, stream>>>(adj, whT, e1, e2, lpart, opart);
    gat_combine<<<out_size / 256, 256, 0, stream>>>(lpart, opart, out);
}